// Round 2
// baseline (283.870 us; speedup 1.0000x reference)
//
#include <hip/hip_runtime.h>

// x: (b=32, t=24, d=10, m=64, n=128) fp32
// out: (b=32, s=12, 1, m=64, n=128) fp32
// (m,n) is a contiguous 8192-float plane per (b,t). One thread per 4
// consecutive n-elements (float4): 65536 threads. Each thread loads a
// 24-deep float4 window (24 x global_load_dwordx4, 16 B/lane = 1 KiB/wave
// per instruction), runs the 12-step EMA recurrence in registers with
// 4-way component ILP, stores 12 float4.

#define B 32
#define T 24
#define D 10
#define MN 8192                     // 64*128, contiguous
#define S_OUT 12
#define IN_T_STRIDE (D * MN)        // 81920 floats
#define IN_B_STRIDE (T * D * MN)    // 1966080 floats
#define OUT_B_STRIDE (S_OUT * MN)   // 98304 floats
#define VEC 4
#define MNV (MN / VEC)              // 2048 float4 per (b,t) plane

__global__ __launch_bounds__(256) void moving_avg_kernel(
    const float4* __restrict__ x4, float4* __restrict__ out4) {
  const int tid = blockIdx.x * blockDim.x + threadIdx.x;  // 0 .. 65535
  const int mnv = tid & (MNV - 1);
  const int b   = tid >> 11;  // tid / 2048

  // EMA coefficients: mu = 0.08, q = 0.92
  // c[j] = q^(T-1)/T + (j < T-1 ? mu * q^(T-2-j) : 0)  -- all compile-time.
  const float mu = 2.0f / (T + 1);
  const float q  = 1.0f - mu;
  float c[T];
  {
    float rec[T];
    float pw = 1.0f;
#pragma unroll
    for (int k = 0; k < T - 1; ++k) { rec[T - 2 - k] = mu * pw; pw *= q; }
    const float base = pw / (float)T;
#pragma unroll
    for (int j = 0; j < T - 1; ++j) c[j] = base + rec[j];
    c[T - 1] = base;
  }

  // Load the 24-deep float4 window (d = 0 slice).
  const float4* xp = x4 + ((long)b * IN_B_STRIDE) / VEC + mnv;
  float4 w[T];
#pragma unroll
  for (int t = 0; t < T; ++t) w[t] = xp[(long)t * (IN_T_STRIDE / VEC)];

  float4* op = out4 + ((long)b * OUT_B_STRIDE) / VEC + mnv;
#pragma unroll
  for (int s = 0; s < S_OUT; ++s) {
    float4 p;
    p.x = 0.0f; p.y = 0.0f; p.z = 0.0f; p.w = 0.0f;
#pragma unroll
    for (int j = 0; j < T; ++j) {
      p.x = fmaf(w[j].x, c[j], p.x);
      p.y = fmaf(w[j].y, c[j], p.y);
      p.z = fmaf(w[j].z, c[j], p.z);
      p.w = fmaf(w[j].w, c[j], p.w);
    }
#pragma unroll
    for (int j = 0; j < T - 1; ++j) w[j] = w[j + 1];
    w[T - 1] = p;
    op[(long)s * (MN / VEC)] = p;
  }
}

extern "C" void kernel_launch(void* const* d_in, const int* in_sizes, int n_in,
                              void* d_out, int out_size, void* d_ws, size_t ws_size,
                              hipStream_t stream) {
  const float4* x4 = (const float4*)d_in[0];
  float4* out4 = (float4*)d_out;
  const int total = B * MNV;  // 65536 threads
  moving_avg_kernel<<<total / 256, 256, 0, stream>>>(x4, out4);
}